// Round 1
// baseline (202.071 us; speedup 1.0000x reference)
//
#include <hip/hip_runtime.h>
#include <hip/hip_bf16.h>
#include <stdint.h>

#define B_ROWS 32768
#define DIM 512
#define BM 128
#define BN 128
#define BK 64
#define THREADS 512

typedef __attribute__((ext_vector_type(8))) __bf16 bf16x8;
typedef __attribute__((ext_vector_type(4))) float f32x4;
typedef __attribute__((ext_vector_type(4))) unsigned int uint4v;

__device__ static inline unsigned short f2bf(float f) {
    unsigned int u = __builtin_bit_cast(unsigned int, f);
    u += 0x7fffu + ((u >> 16) & 1u);
    return (unsigned short)(u >> 16);
}

__device__ static inline void load_lds_16B(const void* g, void* lds) {
    __builtin_amdgcn_global_load_lds(
        (const __attribute__((address_space(1))) unsigned int*)g,
        (__attribute__((address_space(3))) unsigned int*)lds,
        16, 0, 0);
}

// Transpose+concat+bf16+swizzle the 6 weight matrices into
// Wt[3][n=512][k=1024] where element (t,n,k) is stored at k ^ ((n&7)<<3).
// t=0: [Wu_x;Wu_h], t=1: [Wr_x;Wr_h], t=2: [Wc_x;Wc_h].
__global__ void prep_weights(const float* __restrict__ Wu_x, const float* __restrict__ Wu_h,
                             const float* __restrict__ Wr_x, const float* __restrict__ Wr_h,
                             const float* __restrict__ Wc_x, const float* __restrict__ Wc_h,
                             unsigned short* __restrict__ Wt) {
    __shared__ float tile[32][33];
    const int t = blockIdx.z;
    const int k0 = blockIdx.x * 32;   // k in 0..1023
    const int n0 = blockIdx.y * 32;   // n in 0..511
    const float* Wx = (t == 0) ? Wu_x : (t == 1) ? Wr_x : Wc_x;
    const float* Wh = (t == 0) ? Wu_h : (t == 1) ? Wr_h : Wc_h;
    const int tid = threadIdx.x;
    const int c = tid & 31, r0 = tid >> 5;
#pragma unroll
    for (int i = 0; i < 4; ++i) {
        int kl = r0 + i * 8;
        int k = k0 + kl;
        int n = n0 + c;
        float v = (k < 512) ? Wx[(size_t)k * 512 + n] : Wh[(size_t)(k - 512) * 512 + n];
        tile[kl][c] = v;
    }
    __syncthreads();
#pragma unroll
    for (int i = 0; i < 4; ++i) {
        int nl = r0 + i * 8;
        int kl = c;
        int n = n0 + nl, k = k0 + kl;
        Wt[(size_t)t * (512 * 1024) + (size_t)n * 1024 + (k ^ ((n & 7) << 3))] =
            f2bf(tile[kl][nl]);
    }
}

__global__ __launch_bounds__(THREADS, 2) void augru_fused(
    const float* __restrict__ x, const float* __restrict__ h,
    const float* __restrict__ att, const unsigned short* __restrict__ Wt,
    const float* __restrict__ bu, const float* __restrict__ br,
    const float* __restrict__ bc, float* __restrict__ out) {
    __shared__ unsigned short aT[BM * BK];        // 16 KB, XOR-swizzled
    __shared__ unsigned short wT[3 * BN * BK];    // 48 KB, swizzle baked in global
    const int tid = threadIdx.x;
    const int lane = tid & 63;
    const int wid = tid >> 6;
    const int wm = wid >> 2;   // 0..1 -> 64-row half
    const int wn = wid & 3;    // 0..3 -> 32-col quarter
    const int mb = blockIdx.x; // 0..255
    const int nb = blockIdx.y; // 0..3

    f32x4 accU[4][2], accR[4][2], accCx[4][2], accCh[4][2];
#pragma unroll
    for (int i = 0; i < 4; ++i)
#pragma unroll
        for (int j = 0; j < 2; ++j) {
            accU[i][j] = (f32x4)(0.f);
            accR[i][j] = (f32x4)(0.f);
            accCx[i][j] = (f32x4)(0.f);
            accCh[i][j] = (f32x4)(0.f);
        }

    const int arow = tid >> 2;          // 0..127
    const int acol = (tid & 3) * 16;    // element offset within BK
    char* aB = (char*)aT;
    char* wB = (char*)wT;
    const int cl = lane & 15;
    const int kg = lane >> 4;

    auto kstep = [&](const int kt, const float* __restrict__ src, f32x4(&accC)[4][2]) {
        __syncthreads();
        // ---- stage A: 128x64 fp32 -> bf16, swizzled ds_write_b128 x2 ----
        {
            const float* ap = src + (size_t)(mb * BM + arow) * 512 + (kt & 7) * 64 + acol;
            float4 f0 = *(const float4*)(ap + 0);
            float4 f1 = *(const float4*)(ap + 4);
            float4 f2 = *(const float4*)(ap + 8);
            float4 f3 = *(const float4*)(ap + 12);
            uint4v p0, p1;
            p0.x = f2bf(f0.x) | ((unsigned)f2bf(f0.y) << 16);
            p0.y = f2bf(f0.z) | ((unsigned)f2bf(f0.w) << 16);
            p0.z = f2bf(f1.x) | ((unsigned)f2bf(f1.y) << 16);
            p0.w = f2bf(f1.z) | ((unsigned)f2bf(f1.w) << 16);
            p1.x = f2bf(f2.x) | ((unsigned)f2bf(f2.y) << 16);
            p1.y = f2bf(f2.z) | ((unsigned)f2bf(f2.w) << 16);
            p1.z = f2bf(f3.x) | ((unsigned)f2bf(f3.y) << 16);
            p1.w = f2bf(f3.z) | ((unsigned)f2bf(f3.w) << 16);
            const int base = arow * 128 + acol * 2;
            const int sw = (arow & 7) << 4;
            *(uint4v*)(aB + ((base) ^ sw)) = p0;
            *(uint4v*)(aB + ((base + 16) ^ sw)) = p1;
        }
        // ---- stage W: 3x(128n x 64k) bf16 via global_load_lds (16B) ----
#pragma unroll
        for (int it = 0; it < 6; ++it) {
            const int b = it * 8192 + tid * 16;           // byte in 48KB region
            const int t = b >> 14;
            const int bt = b & 16383;
            const int n_l = bt >> 7;
            const int off = bt & 127;                      // byte within 128B k-row
            const unsigned short* g = Wt + (size_t)t * (512 * 1024)
                + (size_t)(nb * BN + n_l) * 1024 + kt * 64 + (off >> 1);
            void* ldsbase = wB + it * 8192 + wid * 1024;   // wave-uniform base
            load_lds_16B(g, ldsbase);
        }
        __syncthreads();
        // ---- compute: 2 k-subtiles x 3 matrices x (4m x 2n) MFMAs ----
#pragma unroll
        for (int ks = 0; ks < 2; ++ks) {
            bf16x8 a[4];
            const int kbyte = ks * 64 + kg * 16;
#pragma unroll
            for (int mi = 0; mi < 4; ++mi) {
                const int row = wm * 64 + mi * 16 + cl;
                const int addr = (row * 128 + kbyte) ^ ((row & 7) << 4);
                a[mi] = __builtin_bit_cast(bf16x8, *(const uint4v*)(aB + addr));
            }
#pragma unroll
            for (int t = 0; t < 3; ++t) {
#pragma unroll
                for (int ni = 0; ni < 2; ++ni) {
                    const int col = wn * 32 + ni * 16 + cl;
                    const int addr = t * 16384 + ((col * 128 + kbyte) ^ ((col & 7) << 4));
                    bf16x8 bfrag = __builtin_bit_cast(bf16x8, *(const uint4v*)(wB + addr));
                    if (t == 0) {
#pragma unroll
                        for (int mi = 0; mi < 4; ++mi)
                            accU[mi][ni] = __builtin_amdgcn_mfma_f32_16x16x32_bf16(
                                a[mi], bfrag, accU[mi][ni], 0, 0, 0);
                    } else if (t == 1) {
#pragma unroll
                        for (int mi = 0; mi < 4; ++mi)
                            accR[mi][ni] = __builtin_amdgcn_mfma_f32_16x16x32_bf16(
                                a[mi], bfrag, accR[mi][ni], 0, 0, 0);
                    } else {
#pragma unroll
                        for (int mi = 0; mi < 4; ++mi)
                            accC[mi][ni] = __builtin_amdgcn_mfma_f32_16x16x32_bf16(
                                a[mi], bfrag, accC[mi][ni], 0, 0, 0);
                    }
                }
            }
        }
    };

    for (int kt = 0; kt < 8; ++kt) kstep(kt, x, accCx);   // k-half from x -> cx
    for (int kt = 8; kt < 16; ++kt) kstep(kt, h, accCh);  // k-half from h -> ch

    // ---- fused epilogue: gates + attention blend ----
#pragma unroll
    for (int mi = 0; mi < 4; ++mi) {
#pragma unroll
        for (int ni = 0; ni < 2; ++ni) {
            const int col = nb * BN + wn * 32 + ni * 16 + cl;
            const float bU = bu[col];
            const float bR = br[col];
            const float bC = bc[col];
#pragma unroll
            for (int j = 0; j < 4; ++j) {
                const int row = mb * BM + wm * 64 + mi * 16 + kg * 4 + j;
                const float up = accU[mi][ni][j] + bU;
                const float rp = accR[mi][ni][j] + bR;
                const float u = 1.f / (1.f + __expf(-up));
                const float r = 1.f / (1.f + __expf(-rp));
                const float cc = tanhf(accCx[mi][ni][j] + bC + r * accCh[mi][ni][j]);
                const float a = att[row];
                const float hv = h[(size_t)row * 512 + col];
                const float u_ = a * u;
                out[(size_t)row * 512 + col] = (1.f - u_) * hv + u_ * cc;
            }
        }
    }
}

extern "C" void kernel_launch(void* const* d_in, const int* in_sizes, int n_in,
                              void* d_out, int out_size, void* d_ws, size_t ws_size,
                              hipStream_t stream) {
    const float* x    = (const float*)d_in[0];
    const float* h    = (const float*)d_in[1];
    const float* att  = (const float*)d_in[2];
    const float* Wu_x = (const float*)d_in[3];
    const float* bu   = (const float*)d_in[4];
    const float* Wu_h = (const float*)d_in[5];
    const float* Wr_x = (const float*)d_in[6];
    const float* br   = (const float*)d_in[7];
    const float* Wr_h = (const float*)d_in[8];
    const float* Wc_x = (const float*)d_in[9];
    const float* bc   = (const float*)d_in[10];
    const float* Wc_h = (const float*)d_in[11];
    unsigned short* Wt = (unsigned short*)d_ws;   // 3*512*1024*2 = 3 MB
    float* out = (float*)d_out;

    prep_weights<<<dim3(32, 16, 3), 256, 0, stream>>>(Wu_x, Wu_h, Wr_x, Wr_h, Wc_x, Wc_h, Wt);
    augru_fused<<<dim3(B_ROWS / BM, DIM / BN), THREADS, 0, stream>>>(
        x, h, att, Wt, bu, br, bc, out);
}

// Round 2
// 174.499 us; speedup vs baseline: 1.1580x; 1.1580x over previous
//
#include <hip/hip_runtime.h>
#include <hip/hip_bf16.h>
#include <stdint.h>

#define B_ROWS 32768
#define DIM 512
#define BM 128
#define BN 128
#define BK 64
#define THREADS 512

typedef __attribute__((ext_vector_type(8))) __bf16 bf16x8;
typedef __attribute__((ext_vector_type(4))) float f32x4;
typedef __attribute__((ext_vector_type(4))) unsigned int uint4v;

__device__ static inline unsigned short f2bf(float f) {
    unsigned int u = __builtin_bit_cast(unsigned int, f);
    u += 0x7fffu + ((u >> 16) & 1u);
    return (unsigned short)(u >> 16);
}

__device__ static inline void load_lds_16B(const void* g, void* lds) {
    __builtin_amdgcn_global_load_lds(
        (const __attribute__((address_space(1))) unsigned int*)g,
        (__attribute__((address_space(3))) unsigned int*)lds,
        16, 0, 0);
}

// ---------------- prep: weights -> Wt[3][n=512][k=1024] bf16, k XOR-swizzled ----
__global__ void prep_weights(const float* __restrict__ Wu_x, const float* __restrict__ Wu_h,
                             const float* __restrict__ Wr_x, const float* __restrict__ Wr_h,
                             const float* __restrict__ Wc_x, const float* __restrict__ Wc_h,
                             unsigned short* __restrict__ Wt) {
    __shared__ float tile[32][33];
    const int t = blockIdx.z;
    const int k0 = blockIdx.x * 32;   // k in 0..1023
    const int n0 = blockIdx.y * 32;   // n in 0..511
    const float* Wx = (t == 0) ? Wu_x : (t == 1) ? Wr_x : Wc_x;
    const float* Wh = (t == 0) ? Wu_h : (t == 1) ? Wr_h : Wc_h;
    const int tid = threadIdx.x;
    const int c = tid & 31, r0 = tid >> 5;
#pragma unroll
    for (int i = 0; i < 4; ++i) {
        int kl = r0 + i * 8;
        int k = k0 + kl;
        int n = n0 + c;
        float v = (k < 512) ? Wx[(size_t)k * 512 + n] : Wh[(size_t)(k - 512) * 512 + n];
        tile[kl][c] = v;
    }
    __syncthreads();
#pragma unroll
    for (int i = 0; i < 4; ++i) {
        int nl = r0 + i * 8;
        int kl = c;
        int n = n0 + nl, k = k0 + kl;
        Wt[(size_t)t * (512 * 1024) + (size_t)n * 1024 + (k ^ ((n & 7) << 3))] =
            f2bf(tile[kl][nl]);
    }
}

// ---------------- prep: A = [x|h] -> bf16, tiled [mb][kt][16KB], swizzle pre-baked
__global__ __launch_bounds__(512) void prep_A(const float* __restrict__ x,
                                              const float* __restrict__ h,
                                              unsigned short* __restrict__ Apack) {
    const int mb = blockIdx.x;      // 0..255
    const int kt = blockIdx.y;      // 0..15 (0-7 from x, 8-15 from h)
    const int tid = threadIdx.x;
    const int arow = tid >> 2;          // 0..127
    const int acol = (tid & 3) * 16;    // 0,16,32,48
    const float* src = (kt < 8) ? x : h;
    const float* ap = src + (size_t)(mb * 128 + arow) * 512 + (kt & 7) * 64 + acol;
    float4 f0 = *(const float4*)(ap + 0);
    float4 f1 = *(const float4*)(ap + 4);
    float4 f2 = *(const float4*)(ap + 8);
    float4 f3 = *(const float4*)(ap + 12);
    uint4v p0, p1;
    p0.x = f2bf(f0.x) | ((unsigned)f2bf(f0.y) << 16);
    p0.y = f2bf(f0.z) | ((unsigned)f2bf(f0.w) << 16);
    p0.z = f2bf(f1.x) | ((unsigned)f2bf(f1.y) << 16);
    p0.w = f2bf(f1.z) | ((unsigned)f2bf(f1.w) << 16);
    p1.x = f2bf(f2.x) | ((unsigned)f2bf(f2.y) << 16);
    p1.y = f2bf(f2.z) | ((unsigned)f2bf(f2.w) << 16);
    p1.z = f2bf(f3.x) | ((unsigned)f2bf(f3.y) << 16);
    p1.w = f2bf(f3.z) | ((unsigned)f2bf(f3.w) << 16);
    char* base = (char*)Apack + (((size_t)mb * 16 + kt) << 14);
    const int b = arow * 128 + acol * 2;
    const int sw = (arow & 7) << 4;
    *(uint4v*)(base + (b ^ sw)) = p0;
    *(uint4v*)(base + ((b + 16) ^ sw)) = p1;
}

// ---------------- main: double-buffered, all staging via global_load_lds --------
__global__ __launch_bounds__(THREADS, 2) void augru_main(
    const float* __restrict__ h, const float* __restrict__ att,
    const unsigned short* __restrict__ Wt, const unsigned short* __restrict__ Apack,
    const float* __restrict__ bu, const float* __restrict__ br,
    const float* __restrict__ bc, float* __restrict__ out) {
    extern __shared__ char smem[];   // 2 x (16KB A + 48KB W) = 128 KB
    const int tid = threadIdx.x;
    const int lane = tid & 63;
    const int wid = tid >> 6;
    const int wm = wid >> 2;   // 0..1
    const int wn = wid & 3;    // 0..3
    // XCD-bijective swizzle: 1024 blocks, 8 XCDs, nb-siblings adjacent in-XCD
    const int id = blockIdx.x;
    const int wg = (id & 7) * 128 + (id >> 3);
    const int nb = wg & 3;
    const int mb = wg >> 2;
    const int cl = lane & 15;
    const int kg = lane >> 4;

    f32x4 accU[4][2], accR[4][2], accCx[4][2], accCh[4][2];
#pragma unroll
    for (int i = 0; i < 4; ++i)
#pragma unroll
        for (int j = 0; j < 2; ++j) {
            accU[i][j] = (f32x4)(0.f);
            accR[i][j] = (f32x4)(0.f);
            accCx[i][j] = (f32x4)(0.f);
            accCh[i][j] = (f32x4)(0.f);
        }

    auto stage = [&](int buf, int kt) {
        // A: 16 KB, linear copy (swizzle pre-baked in Apack)
        const char* srcA = (const char*)Apack + (((size_t)mb * 16 + kt) << 14);
#pragma unroll
        for (int it = 0; it < 2; ++it)
            load_lds_16B(srcA + it * 8192 + tid * 16,
                         smem + buf * 65536 + it * 8192 + wid * 1024);
        // W: 48 KB (3 mats x 128 cols x 128B k-chunk), swizzle pre-baked in Wt
#pragma unroll
        for (int it = 0; it < 6; ++it) {
            const int b = it * 8192 + tid * 16;
            const int t = b >> 14;
            const int n_l = (b & 16383) >> 7;
            const int off = b & 127;
            const char* g = (const char*)Wt + ((size_t)t << 20)
                + (size_t)(nb * 128 + n_l) * 2048 + kt * 128 + off;
            load_lds_16B(g, smem + buf * 65536 + 16384 + it * 8192 + wid * 1024);
        }
    };

    stage(0, 0);
    __syncthreads();

    auto kstep = [&](int kt, f32x4(&accC)[4][2]) {
        const int buf = kt & 1;
        const char* aB = smem + buf * 65536;
        const char* wB = aB + 16384;
        bf16x8 a[2][4];
        bf16x8 bb[2][3][2];
#pragma unroll
        for (int ks = 0; ks < 2; ++ks) {
            const int kbyte = ks * 64 + kg * 16;
#pragma unroll
            for (int mi = 0; mi < 4; ++mi) {
                const int row = wm * 64 + mi * 16 + cl;
                a[ks][mi] = __builtin_bit_cast(
                    bf16x8, *(const uint4v*)(aB + ((row * 128 + kbyte) ^ ((row & 7) << 4))));
            }
#pragma unroll
            for (int t = 0; t < 3; ++t)
#pragma unroll
                for (int ni = 0; ni < 2; ++ni) {
                    const int col = wn * 32 + ni * 16 + cl;
                    bb[ks][t][ni] = __builtin_bit_cast(
                        bf16x8, *(const uint4v*)(wB + t * 16384
                            + ((col * 128 + kbyte) ^ ((col & 7) << 4))));
                }
        }
        if (kt < 15) stage(buf ^ 1, kt + 1);   // prefetch overlaps the MFMAs below
#pragma unroll
        for (int ks = 0; ks < 2; ++ks) {
#pragma unroll
            for (int ni = 0; ni < 2; ++ni) {
#pragma unroll
                for (int mi = 0; mi < 4; ++mi) {
                    accU[mi][ni] = __builtin_amdgcn_mfma_f32_16x16x32_bf16(
                        a[ks][mi], bb[ks][0][ni], accU[mi][ni], 0, 0, 0);
                }
#pragma unroll
                for (int mi = 0; mi < 4; ++mi) {
                    accR[mi][ni] = __builtin_amdgcn_mfma_f32_16x16x32_bf16(
                        a[ks][mi], bb[ks][1][ni], accR[mi][ni], 0, 0, 0);
                }
#pragma unroll
                for (int mi = 0; mi < 4; ++mi) {
                    accC[mi][ni] = __builtin_amdgcn_mfma_f32_16x16x32_bf16(
                        a[ks][mi], bb[ks][2][ni], accC[mi][ni], 0, 0, 0);
                }
            }
        }
        __syncthreads();   // compiler emits vmcnt(0): next buffer ready
    };

    for (int kt = 0; kt < 8; ++kt) kstep(kt, accCx);   // x-half -> cx
    for (int kt = 8; kt < 16; ++kt) kstep(kt, accCh);  // h-half -> ch

    // ---- fused epilogue ----
#pragma unroll
    for (int ni = 0; ni < 2; ++ni) {
        const int col = nb * BN + wn * 32 + ni * 16 + cl;
        const float bU = bu[col];
        const float bR = br[col];
        const float bC = bc[col];
#pragma unroll
        for (int mi = 0; mi < 4; ++mi) {
#pragma unroll
            for (int j = 0; j < 4; ++j) {
                const int row = mb * BM + wm * 64 + mi * 16 + kg * 4 + j;
                const float up = accU[mi][ni][j] + bU;
                const float rp = accR[mi][ni][j] + bR;
                const float u = 1.f / (1.f + __expf(-up));
                const float r = 1.f / (1.f + __expf(-rp));
                const float cc = tanhf(accCx[mi][ni][j] + bC + r * accCh[mi][ni][j]);
                const float a = att[row];
                const float hv = h[(size_t)row * 512 + col];
                const float u_ = a * u;
                out[(size_t)row * 512 + col] = (1.f - u_) * hv + u_ * cc;
            }
        }
    }
}

// ---------------- fallback (round-1 kernel) if ws too small for Apack ----------
__global__ __launch_bounds__(THREADS, 2) void augru_fused_fb(
    const float* __restrict__ x, const float* __restrict__ h,
    const float* __restrict__ att, const unsigned short* __restrict__ Wt,
    const float* __restrict__ bu, const float* __restrict__ br,
    const float* __restrict__ bc, float* __restrict__ out) {
    __shared__ unsigned short aT[BM * BK];
    __shared__ unsigned short wT[3 * BN * BK];
    const int tid = threadIdx.x;
    const int lane = tid & 63;
    const int wid = tid >> 6;
    const int wm = wid >> 2;
    const int wn = wid & 3;
    const int mb = blockIdx.x;
    const int nb = blockIdx.y;

    f32x4 accU[4][2], accR[4][2], accCx[4][2], accCh[4][2];
#pragma unroll
    for (int i = 0; i < 4; ++i)
#pragma unroll
        for (int j = 0; j < 2; ++j) {
            accU[i][j] = (f32x4)(0.f);
            accR[i][j] = (f32x4)(0.f);
            accCx[i][j] = (f32x4)(0.f);
            accCh[i][j] = (f32x4)(0.f);
        }

    const int arow = tid >> 2;
    const int acol = (tid & 3) * 16;
    char* aB = (char*)aT;
    char* wB = (char*)wT;
    const int cl = lane & 15;
    const int kg = lane >> 4;

    auto kstep = [&](const int kt, const float* __restrict__ src, f32x4(&accC)[4][2]) {
        __syncthreads();
        {
            const float* ap = src + (size_t)(mb * BM + arow) * 512 + (kt & 7) * 64 + acol;
            float4 f0 = *(const float4*)(ap + 0);
            float4 f1 = *(const float4*)(ap + 4);
            float4 f2 = *(const float4*)(ap + 8);
            float4 f3 = *(const float4*)(ap + 12);
            uint4v p0, p1;
            p0.x = f2bf(f0.x) | ((unsigned)f2bf(f0.y) << 16);
            p0.y = f2bf(f0.z) | ((unsigned)f2bf(f0.w) << 16);
            p0.z = f2bf(f1.x) | ((unsigned)f2bf(f1.y) << 16);
            p0.w = f2bf(f1.z) | ((unsigned)f2bf(f1.w) << 16);
            p1.x = f2bf(f2.x) | ((unsigned)f2bf(f2.y) << 16);
            p1.y = f2bf(f2.z) | ((unsigned)f2bf(f2.w) << 16);
            p1.z = f2bf(f3.x) | ((unsigned)f2bf(f3.y) << 16);
            p1.w = f2bf(f3.z) | ((unsigned)f2bf(f3.w) << 16);
            const int base = arow * 128 + acol * 2;
            const int sw = (arow & 7) << 4;
            *(uint4v*)(aB + ((base) ^ sw)) = p0;
            *(uint4v*)(aB + ((base + 16) ^ sw)) = p1;
        }
#pragma unroll
        for (int it = 0; it < 6; ++it) {
            const int b = it * 8192 + tid * 16;
            const int t = b >> 14;
            const int bt = b & 16383;
            const int n_l = bt >> 7;
            const int off = bt & 127;
            const unsigned short* g = Wt + (size_t)t * (512 * 1024)
                + (size_t)(nb * BN + n_l) * 1024 + kt * 64 + (off >> 1);
            load_lds_16B(g, wB + it * 8192 + wid * 1024);
        }
        __syncthreads();
#pragma unroll
        for (int ks = 0; ks < 2; ++ks) {
            bf16x8 a[4];
            const int kbyte = ks * 64 + kg * 16;
#pragma unroll
            for (int mi = 0; mi < 4; ++mi) {
                const int row = wm * 64 + mi * 16 + cl;
                a[mi] = __builtin_bit_cast(
                    bf16x8, *(const uint4v*)(aB + ((row * 128 + kbyte) ^ ((row & 7) << 4))));
            }
#pragma unroll
            for (int t = 0; t < 3; ++t) {
#pragma unroll
                for (int ni = 0; ni < 2; ++ni) {
                    const int col = wn * 32 + ni * 16 + cl;
                    bf16x8 bfrag = __builtin_bit_cast(
                        bf16x8, *(const uint4v*)(wB + t * 16384
                            + ((col * 128 + kbyte) ^ ((col & 7) << 4))));
                    if (t == 0) {
#pragma unroll
                        for (int mi = 0; mi < 4; ++mi)
                            accU[mi][ni] = __builtin_amdgcn_mfma_f32_16x16x32_bf16(
                                a[mi], bfrag, accU[mi][ni], 0, 0, 0);
                    } else if (t == 1) {
#pragma unroll
                        for (int mi = 0; mi < 4; ++mi)
                            accR[mi][ni] = __builtin_amdgcn_mfma_f32_16x16x32_bf16(
                                a[mi], bfrag, accR[mi][ni], 0, 0, 0);
                    } else {
#pragma unroll
                        for (int mi = 0; mi < 4; ++mi)
                            accC[mi][ni] = __builtin_amdgcn_mfma_f32_16x16x32_bf16(
                                a[mi], bfrag, accC[mi][ni], 0, 0, 0);
                    }
                }
            }
        }
    };

    for (int kt = 0; kt < 8; ++kt) kstep(kt, x, accCx);
    for (int kt = 8; kt < 16; ++kt) kstep(kt, h, accCh);

#pragma unroll
    for (int ni = 0; ni < 2; ++ni) {
        const int col = nb * BN + wn * 32 + ni * 16 + cl;
        const float bU = bu[col];
        const float bR = br[col];
        const float bC = bc[col];
#pragma unroll
        for (int mi = 0; mi < 4; ++mi) {
#pragma unroll
            for (int j = 0; j < 4; ++j) {
                const int row = mb * BM + wm * 64 + mi * 16 + kg * 4 + j;
                const float up = accU[mi][ni][j] + bU;
                const float rp = accR[mi][ni][j] + bR;
                const float u = 1.f / (1.f + __expf(-up));
                const float r = 1.f / (1.f + __expf(-rp));
                const float cc = tanhf(accCx[mi][ni][j] + bC + r * accCh[mi][ni][j]);
                const float a = att[row];
                const float hv = h[(size_t)row * 512 + col];
                const float u_ = a * u;
                out[(size_t)row * 512 + col] = (1.f - u_) * hv + u_ * cc;
            }
        }
    }
}

extern "C" void kernel_launch(void* const* d_in, const int* in_sizes, int n_in,
                              void* d_out, int out_size, void* d_ws, size_t ws_size,
                              hipStream_t stream) {
    const float* x    = (const float*)d_in[0];
    const float* h    = (const float*)d_in[1];
    const float* att  = (const float*)d_in[2];
    const float* Wu_x = (const float*)d_in[3];
    const float* bu   = (const float*)d_in[4];
    const float* Wu_h = (const float*)d_in[5];
    const float* Wr_x = (const float*)d_in[6];
    const float* br   = (const float*)d_in[7];
    const float* Wr_h = (const float*)d_in[8];
    const float* Wc_x = (const float*)d_in[9];
    const float* bc   = (const float*)d_in[10];
    const float* Wc_h = (const float*)d_in[11];
    unsigned short* Wt = (unsigned short*)d_ws;                    // 3 MB @ 0
    unsigned short* Apack = (unsigned short*)((char*)d_ws + (4 << 20)); // 64 MB @ 4MB
    float* out = (float*)d_out;

    prep_weights<<<dim3(32, 16, 3), 256, 0, stream>>>(Wu_x, Wu_h, Wr_x, Wr_h, Wc_x, Wc_h, Wt);

    const size_t ws_needed = (size_t)(4 << 20) + (size_t)64 * 1024 * 1024;
    if (ws_size >= ws_needed) {
        prep_A<<<dim3(256, 16), 512, 0, stream>>>(x, h, Apack);
        hipFuncSetAttribute((const void*)augru_main,
                            hipFuncAttributeMaxDynamicSharedMemorySize, 131072);
        augru_main<<<dim3(1024), THREADS, 131072, stream>>>(
            h, att, Wt, Apack, bu, br, bc, out);
    } else {
        augru_fused_fb<<<dim3(B_ROWS / BM, DIM / BN), THREADS, 0, stream>>>(
            x, h, att, Wt, bu, br, bc, out);
    }
}